// Round 15
// baseline (5288.433 us; speedup 1.0000x reference)
//
#include <hip/hip_runtime.h>
#include <math.h>

typedef unsigned long long ull;
typedef __attribute__((ext_vector_type(8))) short s16x8;
typedef __attribute__((ext_vector_type(8))) unsigned short u16x8;
typedef __attribute__((ext_vector_type(4))) float f32x4;
typedef __attribute__((ext_vector_type(4))) unsigned int u32x4;

// Problem constants
#define TT 256
#define BB 32
#define VV 4712
#define HH 500
#define FOURH 2000
#define MPRE 8160          // 255*32

// ---------------- workspace layout (float offsets) ----------------
#define OFF_DECPRE 16320000
#define OFF_HR     33100000
#define OFF_DECH   38449920
#define OFF_NLL    42561920
#define RING_U32 16384     // per ring: 8 groups x 2048 f32 slots (2000 used)

__device__ __forceinline__ unsigned short f2b(float f) {
  unsigned int b = __float_as_uint(f);
  b = b + 0x7fffu + ((b >> 16) & 1u);   // round-to-nearest-even bf16
  return (unsigned short)(b >> 16);
}

// HW packed bf16 convert via inline asm (verified r12). NOT hip_bf16.h (r9/r11 NaN).
__device__ __forceinline__ unsigned cvtpk(float lo, float hi) {
  unsigned r;
  asm("v_cvt_pk_bf16_f32 %0, %1, %2" : "=v"(r) : "v"(lo), "v"(hi));
  return r;
}

// fast transcendentals (native v_exp; inf-safe forms; deterministic)
__device__ __forceinline__ float fsig(float x) {
  return 1.0f / (1.0f + __expf(-x));
}
__device__ __forceinline__ float ftanh(float x) {
  return 1.0f - 2.0f / (__expf(2.0f * x) + 1.0f);   // x=+inf -> 1, -inf -> -1
}

// ---------------- bf16 MFMA GEMM, 256x256 tile (unchanged from r13/r14) -------
__global__ __launch_bounds__(512) void gemm_bf16_256(
    const float* __restrict__ A, int lda,
    const float* __restrict__ W, int ldw, int rowmapW,
    int bias_mode, const float* __restrict__ b0, const float* __restrict__ b1,
    float* __restrict__ C, int ldc, int M, int N, int K,
    int ntiles, int swz) {
  __shared__ __align__(16) unsigned short As[2][256 * 40];
  __shared__ __align__(16) unsigned short Bs[2][256 * 40];

  const int tid = threadIdx.x;
  const int lane = tid & 63, wid = tid >> 6;
  const int wm = wid >> 2, wn = wid & 3;        // 2x4 wave grid, wave 128x64
  const int row16 = lane & 15, kq = lane >> 4;
  int mt, nt;
  if (swz) { mt = blockIdx.x & 7; nt = blockIdx.x >> 3; }
  else     { nt = blockIdx.x % ntiles; mt = blockIdx.x / ntiles; }
  const int m0 = mt * 256, n0 = nt * 256;

  const int sr = tid >> 1;          // 0..255 staging row
  const int ks = (tid & 1) << 4;
  int am = m0 + sr; if (am >= M) am = M - 1;
  const float* arow = A + (long)am * lda;
  int nn = n0 + sr; if (nn >= N) nn = N - 1;
  int rn = nn;
  if (rowmapW) { int t = nn >> 5, b = nn & 31; rn = ((255 - t) << 5) + b; }
  const float* wrow = W + (long)rn * ldw;

  f32x4 acc[8][4];
#pragma unroll
  for (int i = 0; i < 8; ++i)
#pragma unroll
    for (int j = 0; j < 4; ++j) acc[i][j] = (f32x4){0.f, 0.f, 0.f, 0.f};

  float4 av[4], wv[4];

#define LOAD_TILE(kt_)                                                      \
  do {                                                                      \
    const int kb_ = (kt_) * 32 + ks;                                        \
    _Pragma("unroll")                                                       \
    for (int q = 0; q < 4; ++q) {                                           \
      const int k_ = kb_ + q * 4; /* K multiple of 4 in all our calls */    \
      if (k_ < K) {                                                         \
        av[q] = *(const float4*)(arow + k_);                                \
        wv[q] = *(const float4*)(wrow + k_);                                \
      } else {                                                              \
        av[q] = make_float4(0.f, 0.f, 0.f, 0.f);                            \
        wv[q] = make_float4(0.f, 0.f, 0.f, 0.f);                            \
      }                                                                     \
    }                                                                       \
  } while (0)

#define CVT_STORE(bq_)                                                      \
  do {                                                                      \
    const u32x4 qa0 = {cvtpk(av[0].x, av[0].y), cvtpk(av[0].z, av[0].w),    \
                       cvtpk(av[1].x, av[1].y), cvtpk(av[1].z, av[1].w)};   \
    const u32x4 qa1 = {cvtpk(av[2].x, av[2].y), cvtpk(av[2].z, av[2].w),    \
                       cvtpk(av[3].x, av[3].y), cvtpk(av[3].z, av[3].w)};   \
    const u32x4 qw0 = {cvtpk(wv[0].x, wv[0].y), cvtpk(wv[0].z, wv[0].w),    \
                       cvtpk(wv[1].x, wv[1].y), cvtpk(wv[1].z, wv[1].w)};   \
    const u32x4 qw1 = {cvtpk(wv[2].x, wv[2].y), cvtpk(wv[2].z, wv[2].w),    \
                       cvtpk(wv[3].x, wv[3].y), cvtpk(wv[3].z, wv[3].w)};   \
    *(u32x4*)&As[bq_][sr * 40 + ks + 0] = qa0;                              \
    *(u32x4*)&As[bq_][sr * 40 + ks + 8] = qa1;                              \
    *(u32x4*)&Bs[bq_][sr * 40 + ks + 0] = qw0;                              \
    *(u32x4*)&Bs[bq_][sr * 40 + ks + 8] = qw1;                              \
  } while (0)

  // prologue: tile 0 -> buffer 0
  LOAD_TILE(0);
  CVT_STORE(0);
  __syncthreads();

  const int KT = (K + 31) >> 5;
  for (int kt = 0; kt < KT; ++kt) {
    const int cur = kt & 1;
    const bool more = (kt + 1 < KT);
    if (more) LOAD_TILE(kt + 1);   // issue loads; complete under MFMA below

    s16x8 afrag[8], bfrag[4];
#pragma unroll
    for (int i = 0; i < 8; ++i)
      afrag[i] = *(const s16x8*)&As[cur][(wm * 128 + i * 16 + row16) * 40 + kq * 8];
#pragma unroll
    for (int j = 0; j < 4; ++j)
      bfrag[j] = *(const s16x8*)&Bs[cur][(wn * 64 + j * 16 + row16) * 40 + kq * 8];
#pragma unroll
    for (int i = 0; i < 8; ++i)
#pragma unroll
      for (int j = 0; j < 4; ++j)
        acc[i][j] = __builtin_amdgcn_mfma_f32_16x16x32_bf16(
            afrag[i], bfrag[j], acc[i][j], 0, 0, 0);

    if (more) {
      CVT_STORE(cur ^ 1);          // other buffer; prior reads done at the
      __syncthreads();             // previous barrier -> safe
    }
  }
#undef LOAD_TILE
#undef CVT_STORE

#pragma unroll
  for (int i = 0; i < 8; ++i) {
    const int rbase = m0 + wm * 128 + i * 16 + kq * 4;
#pragma unroll
    for (int r = 0; r < 4; ++r) {
      const int mrow = rbase + r;
      if (mrow < M) {
        const float rb = (bias_mode == 1) ? (b0[mrow] + b1[mrow]) : 0.0f;
        float* crow = C + (long)mrow * ldc;
#pragma unroll
        for (int j = 0; j < 4; ++j) {
          const int col = n0 + wn * 64 + j * 16 + row16;
          if (col < N) {
            float v = acc[i][j][r] + rb;
            if (bias_mode == 0 && b0) v += b0[col];
            crow[col] = v;
          }
        }
      }
    }
  }
}

// ---------------- persistent LSTM recurrence: sentinel + plain-f32 ring -------
// v3 sync protocol: detection is SEPARATED from data.
//   producer: store 4B f32 ring values (relaxed IC atomics) -> __syncthreads
//   (drains vmcnt: stores ACKed at coherence point) -> tid0 release-stores a
//   per-block step SENTINEL.
//   consumer: poll only the 32 sentinels of its group (128B/round, ~100x less
//   IC traffic than polling 2000 tagged slots) -> ONE coalesced gather round.
// Ring depth 3: producer writes ring[(s+2)%3] only after all sentinels >= s+1,
// which implies every block finished reading ring[(s-1)%3].
#define PITCH_H 544
__global__ __launch_bounds__(256) void lstm_rec(
    const float* __restrict__ enc_preT, const float* __restrict__ dec_preT,
    const float* __restrict__ enc_Whh, const float* __restrict__ dec_Whh,
    unsigned* __restrict__ hring, unsigned* __restrict__ sent,
    float* __restrict__ dec_h) {
  __shared__ __align__(16) unsigned short hb16[2][4 * PITCH_H];  // 8.5 KB

  const int tid = threadIdx.x;
  const int lane = tid & 63, w = tid >> 6;
  const int kq = lane >> 4;             // 0..3
  const int X = blockIdx.x & 31, Y = blockIdx.x >> 5;
  const int u0 = X * 16, b0 = Y * 4;
  const int gbase = Y * 2048;           // group's slot base within a ring
  unsigned* gsent = sent + Y * 32;      // group's 32 sentinels

  const int arr = lane & 15;
  const int ag  = arr & 3;
  const int au  = u0 + w * 4 + (arr >> 2);
  const bool auok = (au < 500);

  const int c    = lane & 15;           // batch col (active if <4)
  const int uout = u0 + w * 4 + kq;
  const bool act = (c < 4) && (uout < 500);
  long preoff[4];
#pragma unroll
  for (int g = 0; g < 4; ++g)
    preoff[g] = (long)(g * 500 + (act ? uout : 0)) * MPRE + b0 + (act ? c : 0);

  if (tid < 352) {
    const int bq = tid / 176, rr = tid % 176;
    const int cc = rr / 44, k = 500 + rr % 44;
    hb16[bq][cc * PITCH_H + k] = 0;
  }
  __syncthreads();

  float creg = 0.0f;   // cell state (uout, b0+c) on active lanes

  const float* pres[2] = {enc_preT, dec_preT};
  const float* whhs[2] = {enc_Whh, dec_Whh};
  unsigned step = 0;   // global step 1..510 across both phases

  for (int ph = 0; ph < 2; ++ph) {
    const float* pre = pres[ph];
    const float* Whh = whhs[ph];

    s16x8 afrag[16];
    {
      const float* wrow = Whh + (long)(ag * 500 + (auok ? au : 0)) * 500;
#pragma unroll
      for (int ch = 0; ch < 16; ++ch) {
        const int k0 = ch * 32 + kq * 8;
        float4 v0 = make_float4(0.f, 0.f, 0.f, 0.f);
        float4 v1 = make_float4(0.f, 0.f, 0.f, 0.f);
        if (auok && k0 < 500)     v0 = *(const float4*)(wrow + k0);
        if (auok && k0 + 4 < 500) v1 = *(const float4*)(wrow + k0 + 4);
        const u16x8 p = {f2b(v0.x), f2b(v0.y), f2b(v0.z), f2b(v0.w),
                         f2b(v1.x), f2b(v1.y), f2b(v1.z), f2b(v1.w)};
        afrag[ch] = (s16x8)p;
      }
    }

    for (int t = 0; t < 255; ++t) {
      ++step;
      const unsigned want = step - 1;
      const int buf = step & 1;
      const unsigned* rring = hring + (ull)((step - 1) % 3) * RING_U32 + gbase;
      unsigned* wring = hring + (ull)(step % 3) * RING_U32 + gbase;

      float pv[4];
#pragma unroll
      for (int g = 0; g < 4; ++g) pv[g] = pre[preoff[g] + t * 32];

      // 1) poll the 32 producer sentinels of this group (128B per round)
      if (tid < 32) {
        while (__hip_atomic_load(&gsent[tid], __ATOMIC_RELAXED,
                                 __HIP_MEMORY_SCOPE_AGENT) < want) {
          __builtin_amdgcn_s_sleep(1);
        }
      }
      __syncthreads();

      // 2) single-round coalesced gather (slot s -> u=s>>2, c=s&3)
#pragma unroll
      for (int j = 0; j < 8; ++j) {
        const int s = tid + j * 256;
        const unsigned v = __hip_atomic_load(&rring[s], __ATOMIC_RELAXED,
                                             __HIP_MEMORY_SCOPE_AGENT);
        if (s < 2000)
          hb16[buf][(s & 3) * PITCH_H + (s >> 2)] = f2b(__uint_as_float(v));
      }
      __syncthreads();

      // 3) 16 MFMA + gates
      f32x4 acc = (f32x4){0.f, 0.f, 0.f, 0.f};
      const unsigned short* hbase = &hb16[buf][(c & 3) * PITCH_H + kq * 8];
#pragma unroll
      for (int ch = 0; ch < 16; ++ch) {
        const s16x8 bfrag = *(const s16x8*)(hbase + ch * 32);
        acc = __builtin_amdgcn_mfma_f32_16x16x32_bf16(afrag[ch], bfrag, acc,
                                                      0, 0, 0);
      }

      if (act) {
        const float iv = acc[0] + pv[0];
        const float fv = acc[1] + pv[1];
        const float gv = acc[2] + pv[2];
        const float ov = acc[3] + pv[3];
        const float cn = fsig(fv) * creg + fsig(iv) * ftanh(gv);
        const float hn = fsig(ov) * ftanh(cn);
        creg = cn;
        __hip_atomic_store(&wring[(uout << 2) + c], __float_as_uint(hn),
                           __ATOMIC_RELAXED, __HIP_MEMORY_SCOPE_AGENT);
        if (ph == 1)
          dec_h[(long)(t * 32 + b0 + c) * 500 + uout] = hn;
      }

      // 4) publish: barrier drains each wave's vmcnt (h stores ACKed at the
      // coherence point), then sentinel release-store.
      __syncthreads();
      if (tid == 0)
        __hip_atomic_store(&gsent[X], step, __ATOMIC_RELEASE,
                           __HIP_MEMORY_SCOPE_AGENT);
    }
  }
}

// ---------------- per-row log-softmax NLL ----------------
__device__ __forceinline__ float wave_max(float v) {
#pragma unroll
  for (int o = 32; o > 0; o >>= 1) v = fmaxf(v, __shfl_xor(v, o, 64));
  return v;
}
__device__ __forceinline__ float wave_sum(float v) {
#pragma unroll
  for (int o = 32; o > 0; o >>= 1) v += __shfl_xor(v, o, 64);
  return v;
}

__global__ __launch_bounds__(256) void loss_rows(
    const float* __restrict__ seq, const float* __restrict__ logits,
    const int* __restrict__ nseq, float* __restrict__ nll) {
  __shared__ float sm[8];
  const int r = blockIdx.x, tid = threadIdx.x;
  const int t = r >> 5, b = r & 31;
  const float* row = (t == 0) ? (seq + (long)b * VV)
                              : (logits + (long)((t - 1) * 32 + b) * VV);
  float m = -INFINITY;
  for (int c = tid; c < 1178; c += 256) {
    float4 v = *(const float4*)&row[c * 4];
    m = fmaxf(m, fmaxf(fmaxf(v.x, v.y), fmaxf(v.z, v.w)));
  }
  m = wave_max(m);
  const int wid = tid >> 6;
  if ((tid & 63) == 0) sm[wid] = m;
  __syncthreads();
  const float M4 = fmaxf(fmaxf(sm[0], sm[1]), fmaxf(sm[2], sm[3]));
  float s = 0.0f;
  for (int c = tid; c < 1178; c += 256) {
    float4 v = *(const float4*)&row[c * 4];
    s += expf(v.x - M4) + expf(v.y - M4) + expf(v.z - M4) + expf(v.w - M4);
  }
  s = wave_sum(s);
  if ((tid & 63) == 0) sm[4 + wid] = s;
  __syncthreads();
  if (tid == 0) {
    const float S = sm[4] + sm[5] + sm[6] + sm[7];
    const int tgt = nseq[(t << 5) + b];
    nll[r] = M4 + logf(S) - row[tgt];
  }
}

__global__ __launch_bounds__(256) void final_reduce(
    const float* __restrict__ nll, float* __restrict__ out) {
  __shared__ float sm[4];
  float s = 0.0f;
  for (int c = threadIdx.x; c < 8192; c += 256) s += nll[c];
  s = wave_sum(s);
  if ((threadIdx.x & 63) == 0) sm[threadIdx.x >> 6] = s;
  __syncthreads();
  if (threadIdx.x == 0) out[0] = (sm[0] + sm[1] + sm[2] + sm[3]) * (1.0f / 8192.0f);
}

// ---------------- launch ----------------
extern "C" void kernel_launch(void* const* d_in, const int* in_sizes, int n_in,
                              void* d_out, int out_size, void* d_ws, size_t ws_size,
                              hipStream_t stream) {
  (void)in_sizes; (void)n_in; (void)out_size; (void)ws_size;
  const float* seq  = (const float*)d_in[0];
  const int* nseq   = (const int*)d_in[1];
  const float* eWih = (const float*)d_in[2];
  const float* eWhh = (const float*)d_in[3];
  const float* ebih = (const float*)d_in[4];
  const float* ebhh = (const float*)d_in[5];
  const float* dWih = (const float*)d_in[6];
  const float* dWhh = (const float*)d_in[7];
  const float* dbih = (const float*)d_in[8];
  const float* dbhh = (const float*)d_in[9];
  const float* oW   = (const float*)d_in[10];
  const float* ob   = (const float*)d_in[11];

  float* wsf = (float*)d_ws;
  float* logits   = wsf;
  float* enc_preT = wsf;
  float* dec_preT = wsf + OFF_DECPRE;
  unsigned* hring = (unsigned*)(wsf + OFF_HR);
  unsigned* sent  = hring + 3 * RING_U32;
  float* dec_h    = wsf + OFF_DECH;
  float* nll      = wsf + OFF_NLL;

  // rings (f32 0.0 = initial h^0) + sentinels (step 0)
  hipMemsetAsync(hring, 0, (3 * RING_U32 + 256) * sizeof(unsigned), stream);

  // enc_preT[j][t*32+b] = eWih[j,:] . seq[(255-t)*32+b,:] + ebih[j]+ebhh[j]
  gemm_bf16_256<<<dim3(256), dim3(512), 0, stream>>>(
      eWih, VV, seq, VV, 1, 1, ebih, ebhh,
      enc_preT, MPRE, FOURH, MPRE, VV, 32, 1);
  // dec_preT[j][t*32+b] = dWih[j,:] . seq[t*32+b,:] + dbih[j]+dbhh[j]
  gemm_bf16_256<<<dim3(256), dim3(512), 0, stream>>>(
      dWih, VV, seq, VV, 0, 1, dbih, dbhh,
      dec_preT, MPRE, FOURH, MPRE, VV, 32, 1);
  // recurrence (encoder then decoder), writes dec_h
  lstm_rec<<<dim3(256), dim3(256), 0, stream>>>(enc_preT, dec_preT, eWhh, dWhh,
                                                hring, sent, dec_h);
  // logits = dec_h @ out_W^T + out_b  (32 mtiles x 19 ntiles = 608 blocks)
  gemm_bf16_256<<<dim3(608), dim3(512), 0, stream>>>(
      dec_h, HH, oW, HH, 0, 0, ob, nullptr,
      logits, VV, MPRE, VV, HH, 19, 0);
  // per-row NLL then deterministic reduce
  loss_rows<<<dim3(8192), dim3(256), 0, stream>>>(seq, logits, nseq, nll);
  final_reduce<<<dim3(1), dim3(256), 0, stream>>>(nll, (float*)d_out);
}

// Round 16
// 2735.263 us; speedup vs baseline: 1.9334x; 1.9334x over previous
//
#include <hip/hip_runtime.h>
#include <math.h>

typedef unsigned long long ull;
typedef __attribute__((ext_vector_type(8))) short s16x8;
typedef __attribute__((ext_vector_type(8))) unsigned short u16x8;
typedef __attribute__((ext_vector_type(4))) float f32x4;
typedef __attribute__((ext_vector_type(4))) unsigned int u32x4;

// Problem constants
#define TT 256
#define BB 32
#define VV 4712
#define HH 500
#define FOURH 2000
#define MPRE 8160          // 255*32

// ---------------- workspace layout (float offsets) ----------------
#define OFF_DECPRE 16320000
#define OFF_HR     33100000
#define OFF_DECH   38449920
#define OFF_NLL    42561920
#define RING_SLOTS 16384   // 8B slots per ring; per group: 2048 (1000 used)

__device__ __forceinline__ unsigned short f2b(float f) {
  unsigned int b = __float_as_uint(f);
  b = b + 0x7fffu + ((b >> 16) & 1u);   // round-to-nearest-even bf16
  return (unsigned short)(b >> 16);
}

// HW packed bf16 convert via inline asm (verified r12). NOT hip_bf16.h (r9/r11 NaN).
__device__ __forceinline__ unsigned cvtpk(float lo, float hi) {
  unsigned r;
  asm("v_cvt_pk_bf16_f32 %0, %1, %2" : "=v"(r) : "v"(lo), "v"(hi));
  return r;
}

// fast transcendentals (native v_exp; inf-safe forms; deterministic)
__device__ __forceinline__ float fsig(float x) {
  return 1.0f / (1.0f + __expf(-x));
}
__device__ __forceinline__ float ftanh(float x) {
  return 1.0f - 2.0f / (__expf(2.0f * x) + 1.0f);   // x=+inf -> 1, -inf -> -1
}

// ---------------- bf16 MFMA GEMM, 256x256 tile (unchanged from r13/r14) -------
__global__ __launch_bounds__(512) void gemm_bf16_256(
    const float* __restrict__ A, int lda,
    const float* __restrict__ W, int ldw, int rowmapW,
    int bias_mode, const float* __restrict__ b0, const float* __restrict__ b1,
    float* __restrict__ C, int ldc, int M, int N, int K,
    int ntiles, int swz) {
  __shared__ __align__(16) unsigned short As[2][256 * 40];
  __shared__ __align__(16) unsigned short Bs[2][256 * 40];

  const int tid = threadIdx.x;
  const int lane = tid & 63, wid = tid >> 6;
  const int wm = wid >> 2, wn = wid & 3;        // 2x4 wave grid, wave 128x64
  const int row16 = lane & 15, kq = lane >> 4;
  int mt, nt;
  if (swz) { mt = blockIdx.x & 7; nt = blockIdx.x >> 3; }
  else     { nt = blockIdx.x % ntiles; mt = blockIdx.x / ntiles; }
  const int m0 = mt * 256, n0 = nt * 256;

  const int sr = tid >> 1;          // 0..255 staging row
  const int ks = (tid & 1) << 4;
  int am = m0 + sr; if (am >= M) am = M - 1;
  const float* arow = A + (long)am * lda;
  int nn = n0 + sr; if (nn >= N) nn = N - 1;
  int rn = nn;
  if (rowmapW) { int t = nn >> 5, b = nn & 31; rn = ((255 - t) << 5) + b; }
  const float* wrow = W + (long)rn * ldw;

  f32x4 acc[8][4];
#pragma unroll
  for (int i = 0; i < 8; ++i)
#pragma unroll
    for (int j = 0; j < 4; ++j) acc[i][j] = (f32x4){0.f, 0.f, 0.f, 0.f};

  float4 av[4], wv[4];

#define LOAD_TILE(kt_)                                                      \
  do {                                                                      \
    const int kb_ = (kt_) * 32 + ks;                                        \
    _Pragma("unroll")                                                       \
    for (int q = 0; q < 4; ++q) {                                           \
      const int k_ = kb_ + q * 4; /* K multiple of 4 in all our calls */    \
      if (k_ < K) {                                                         \
        av[q] = *(const float4*)(arow + k_);                                \
        wv[q] = *(const float4*)(wrow + k_);                                \
      } else {                                                              \
        av[q] = make_float4(0.f, 0.f, 0.f, 0.f);                            \
        wv[q] = make_float4(0.f, 0.f, 0.f, 0.f);                            \
      }                                                                     \
    }                                                                       \
  } while (0)

#define CVT_STORE(bq_)                                                      \
  do {                                                                      \
    const u32x4 qa0 = {cvtpk(av[0].x, av[0].y), cvtpk(av[0].z, av[0].w),    \
                       cvtpk(av[1].x, av[1].y), cvtpk(av[1].z, av[1].w)};   \
    const u32x4 qa1 = {cvtpk(av[2].x, av[2].y), cvtpk(av[2].z, av[2].w),    \
                       cvtpk(av[3].x, av[3].y), cvtpk(av[3].z, av[3].w)};   \
    const u32x4 qw0 = {cvtpk(wv[0].x, wv[0].y), cvtpk(wv[0].z, wv[0].w),    \
                       cvtpk(wv[1].x, wv[1].y), cvtpk(wv[1].z, wv[1].w)};   \
    const u32x4 qw1 = {cvtpk(wv[2].x, wv[2].y), cvtpk(wv[2].z, wv[2].w),    \
                       cvtpk(wv[3].x, wv[3].y), cvtpk(wv[3].z, wv[3].w)};   \
    *(u32x4*)&As[bq_][sr * 40 + ks + 0] = qa0;                              \
    *(u32x4*)&As[bq_][sr * 40 + ks + 8] = qa1;                              \
    *(u32x4*)&Bs[bq_][sr * 40 + ks + 0] = qw0;                              \
    *(u32x4*)&Bs[bq_][sr * 40 + ks + 8] = qw1;                              \
  } while (0)

  // prologue: tile 0 -> buffer 0
  LOAD_TILE(0);
  CVT_STORE(0);
  __syncthreads();

  const int KT = (K + 31) >> 5;
  for (int kt = 0; kt < KT; ++kt) {
    const int cur = kt & 1;
    const bool more = (kt + 1 < KT);
    if (more) LOAD_TILE(kt + 1);   // issue loads; complete under MFMA below

    s16x8 afrag[8], bfrag[4];
#pragma unroll
    for (int i = 0; i < 8; ++i)
      afrag[i] = *(const s16x8*)&As[cur][(wm * 128 + i * 16 + row16) * 40 + kq * 8];
#pragma unroll
    for (int j = 0; j < 4; ++j)
      bfrag[j] = *(const s16x8*)&Bs[cur][(wn * 64 + j * 16 + row16) * 40 + kq * 8];
#pragma unroll
    for (int i = 0; i < 8; ++i)
#pragma unroll
      for (int j = 0; j < 4; ++j)
        acc[i][j] = __builtin_amdgcn_mfma_f32_16x16x32_bf16(
            afrag[i], bfrag[j], acc[i][j], 0, 0, 0);

    if (more) {
      CVT_STORE(cur ^ 1);          // other buffer; prior reads done at the
      __syncthreads();             // previous barrier -> safe
    }
  }
#undef LOAD_TILE
#undef CVT_STORE

#pragma unroll
  for (int i = 0; i < 8; ++i) {
    const int rbase = m0 + wm * 128 + i * 16 + kq * 4;
#pragma unroll
    for (int r = 0; r < 4; ++r) {
      const int mrow = rbase + r;
      if (mrow < M) {
        const float rb = (bias_mode == 1) ? (b0[mrow] + b1[mrow]) : 0.0f;
        float* crow = C + (long)mrow * ldc;
#pragma unroll
        for (int j = 0; j < 4; ++j) {
          const int col = n0 + wn * 64 + j * 16 + row16;
          if (col < N) {
            float v = acc[i][j][r] + rb;
            if (bias_mode == 0 && b0) v += b0[col];
            crow[col] = v;
          }
        }
      }
    }
  }
}

// ---------------- persistent LSTM recurrence: tagged-ring v3 (packed pairs) ---
// r14 protocol (progressive per-arrival gather — r15 proved batch-signaling
// serializes and loses 2x) with HALF the slots: producers pair adjacent units
// via __shfl_xor(hn,16) and store {tag32 | bf16(h_u) | bf16(h_{u+1})} in one
// 8B relaxed IC atomic. 1000 slots/group (was 2000), gather 8KB/block/step
// (was 16KB), consumer-side f2b eliminated (payload already bf16 — identical
// bits to r14's conversion, numerics unchanged).
#define PITCH_H 544
__global__ __launch_bounds__(256) void lstm_rec(
    const float* __restrict__ enc_preT, const float* __restrict__ dec_preT,
    const float* __restrict__ enc_Whh, const float* __restrict__ dec_Whh,
    ull* __restrict__ hring, float* __restrict__ dec_h) {
  __shared__ __align__(16) unsigned short hb16[2][4 * PITCH_H];  // 8.5 KB

  const int tid = threadIdx.x;
  const int lane = tid & 63, w = tid >> 6;
  const int kq = lane >> 4;             // 0..3
  const int X = blockIdx.x & 31, Y = blockIdx.x >> 5;
  const int u0 = X * 16, b0 = Y * 4;
  const int gbase = Y * 2048;           // group's slot base within a ring

  const int arr = lane & 15;
  const int ag  = arr & 3;
  const int au  = u0 + w * 4 + (arr >> 2);
  const bool auok = (au < 500);

  const int c    = lane & 15;           // batch col (active if <4)
  const int uout = u0 + w * 4 + kq;
  const bool act = (c < 4) && (uout < 500);
  long preoff[4];
#pragma unroll
  for (int g = 0; g < 4; ++g)
    preoff[g] = (long)(g * 500 + (act ? uout : 0)) * MPRE + b0 + (act ? c : 0);

  if (tid < 352) {
    const int bq = tid / 176, rr = tid % 176;
    const int cc = rr / 44, k = 500 + rr % 44;
    hb16[bq][cc * PITCH_H + k] = 0;
  }
  __syncthreads();

  float creg = 0.0f;   // cell state (uout, b0+c) on active lanes

  const float* pres[2] = {enc_preT, dec_preT};
  const float* whhs[2] = {enc_Whh, dec_Whh};
  unsigned step = 0;   // global step 1..510 across both phases

  for (int ph = 0; ph < 2; ++ph) {
    const float* pre = pres[ph];
    const float* Whh = whhs[ph];

    s16x8 afrag[16];
    {
      const float* wrow = Whh + (long)(ag * 500 + (auok ? au : 0)) * 500;
#pragma unroll
      for (int ch = 0; ch < 16; ++ch) {
        const int k0 = ch * 32 + kq * 8;
        float4 v0 = make_float4(0.f, 0.f, 0.f, 0.f);
        float4 v1 = make_float4(0.f, 0.f, 0.f, 0.f);
        if (auok && k0 < 500)     v0 = *(const float4*)(wrow + k0);
        if (auok && k0 + 4 < 500) v1 = *(const float4*)(wrow + k0 + 4);
        const u16x8 p = {f2b(v0.x), f2b(v0.y), f2b(v0.z), f2b(v0.w),
                         f2b(v1.x), f2b(v1.y), f2b(v1.z), f2b(v1.w)};
        afrag[ch] = (s16x8)p;
      }
    }

    for (int t = 0; t < 255; ++t) {
      ++step;
      const unsigned want = step - 1;
      const int buf = step & 1;
      const ull* rring = hring + (ull)((step - 1) % 3) * RING_SLOTS + gbase;
      ull* wring = hring + (ull)(step % 3) * RING_SLOTS + gbase;

      float pv[4];
#pragma unroll
      for (int g = 0; g < 4; ++g) pv[g] = pre[preoff[g] + t * 32];

      // poll-gather 1000 packed slots: s -> pair p=s>>2 (units 2p,2p+1), c=s&3.
      // Per-arrival LDS write (progressive availability — the r15 lesson).
      unsigned pend = (tid < 232) ? 0xfu : 0x7u;
      while (pend) {
        unsigned np = pend;
#pragma unroll
        for (int j = 0; j < 4; ++j) {
          if (np & (1u << j)) {
            const int s = tid + j * 256;
            const ull v = __hip_atomic_load(&rring[s], __ATOMIC_RELAXED,
                                            __HIP_MEMORY_SCOPE_AGENT);
            if ((unsigned)(v >> 32) >= want) {
              // payload = two bf16 (low = unit 2p, high = unit 2p+1)
              *(unsigned*)&hb16[buf][(s & 3) * PITCH_H + ((s >> 2) << 1)] =
                  (unsigned)(v & 0xffffffffu);
              np &= ~(1u << j);
            }
          }
        }
        pend = np;
        if (pend) __builtin_amdgcn_s_sleep(1);
      }
      __syncthreads();

      f32x4 acc = (f32x4){0.f, 0.f, 0.f, 0.f};
      const unsigned short* hbase = &hb16[buf][(c & 3) * PITCH_H + kq * 8];
#pragma unroll
      for (int ch = 0; ch < 16; ++ch) {
        const s16x8 bfrag = *(const s16x8*)(hbase + ch * 32);
        acc = __builtin_amdgcn_mfma_f32_16x16x32_bf16(afrag[ch], bfrag, acc,
                                                      0, 0, 0);
      }

      // gates on all lanes (inactive lanes compute garbage, never stored)
      const float iv = acc[0] + pv[0];
      const float fv = acc[1] + pv[1];
      const float gv = acc[2] + pv[2];
      const float ov = acc[3] + pv[3];
      const float cn = fsig(fv) * creg + fsig(iv) * ftanh(gv);
      const float hn = fsig(ov) * ftanh(cn);
      creg = cn;

      // pair exchange: kq0<->kq1, kq2<->kq3 (lane bit 4)
      const float hp = __shfl_xor(hn, 16);
      if (act) {
        if ((kq & 1) == 0) {
          // this lane owns even unit; partner hp is unit uout+1 (<500 proven)
          const unsigned payload =
              (unsigned)f2b(hn) | ((unsigned)f2b(hp) << 16);
          __hip_atomic_store(&wring[((uout >> 1) << 2) + c],
                             ((ull)step << 32) | payload,
                             __ATOMIC_RELAXED, __HIP_MEMORY_SCOPE_AGENT);
        }
        if (ph == 1)
          dec_h[(long)(t * 32 + b0 + c) * 500 + uout] = hn;
      }
    }
  }
}

// ---------------- per-row log-softmax NLL ----------------
__device__ __forceinline__ float wave_max(float v) {
#pragma unroll
  for (int o = 32; o > 0; o >>= 1) v = fmaxf(v, __shfl_xor(v, o, 64));
  return v;
}
__device__ __forceinline__ float wave_sum(float v) {
#pragma unroll
  for (int o = 32; o > 0; o >>= 1) v += __shfl_xor(v, o, 64);
  return v;
}

__global__ __launch_bounds__(256) void loss_rows(
    const float* __restrict__ seq, const float* __restrict__ logits,
    const int* __restrict__ nseq, float* __restrict__ nll) {
  __shared__ float sm[8];
  const int r = blockIdx.x, tid = threadIdx.x;
  const int t = r >> 5, b = r & 31;
  const float* row = (t == 0) ? (seq + (long)b * VV)
                              : (logits + (long)((t - 1) * 32 + b) * VV);
  float m = -INFINITY;
  for (int c = tid; c < 1178; c += 256) {
    float4 v = *(const float4*)&row[c * 4];
    m = fmaxf(m, fmaxf(fmaxf(v.x, v.y), fmaxf(v.z, v.w)));
  }
  m = wave_max(m);
  const int wid = tid >> 6;
  if ((tid & 63) == 0) sm[wid] = m;
  __syncthreads();
  const float M4 = fmaxf(fmaxf(sm[0], sm[1]), fmaxf(sm[2], sm[3]));
  float s = 0.0f;
  for (int c = tid; c < 1178; c += 256) {
    float4 v = *(const float4*)&row[c * 4];
    s += expf(v.x - M4) + expf(v.y - M4) + expf(v.z - M4) + expf(v.w - M4);
  }
  s = wave_sum(s);
  if ((tid & 63) == 0) sm[4 + wid] = s;
  __syncthreads();
  if (tid == 0) {
    const float S = sm[4] + sm[5] + sm[6] + sm[7];
    const int tgt = nseq[(t << 5) + b];
    nll[r] = M4 + logf(S) - row[tgt];
  }
}

__global__ __launch_bounds__(256) void final_reduce(
    const float* __restrict__ nll, float* __restrict__ out) {
  __shared__ float sm[4];
  float s = 0.0f;
  for (int c = threadIdx.x; c < 8192; c += 256) s += nll[c];
  s = wave_sum(s);
  if ((threadIdx.x & 63) == 0) sm[threadIdx.x >> 6] = s;
  __syncthreads();
  if (threadIdx.x == 0) out[0] = (sm[0] + sm[1] + sm[2] + sm[3]) * (1.0f / 8192.0f);
}

// ---------------- launch ----------------
extern "C" void kernel_launch(void* const* d_in, const int* in_sizes, int n_in,
                              void* d_out, int out_size, void* d_ws, size_t ws_size,
                              hipStream_t stream) {
  (void)in_sizes; (void)n_in; (void)out_size; (void)ws_size;
  const float* seq  = (const float*)d_in[0];
  const int* nseq   = (const int*)d_in[1];
  const float* eWih = (const float*)d_in[2];
  const float* eWhh = (const float*)d_in[3];
  const float* ebih = (const float*)d_in[4];
  const float* ebhh = (const float*)d_in[5];
  const float* dWih = (const float*)d_in[6];
  const float* dWhh = (const float*)d_in[7];
  const float* dbih = (const float*)d_in[8];
  const float* dbhh = (const float*)d_in[9];
  const float* oW   = (const float*)d_in[10];
  const float* ob   = (const float*)d_in[11];

  float* wsf = (float*)d_ws;
  float* logits   = wsf;
  float* enc_preT = wsf;
  float* dec_preT = wsf + OFF_DECPRE;
  ull*   hring    = (ull*)(wsf + OFF_HR);
  float* dec_h    = wsf + OFF_DECH;
  float* nll      = wsf + OFF_NLL;

  // rings: {tag 0 | bf16 pair 0,0} everywhere == initial h^0 for want=0
  hipMemsetAsync(hring, 0, 3 * RING_SLOTS * sizeof(ull), stream);

  // enc_preT[j][t*32+b] = eWih[j,:] . seq[(255-t)*32+b,:] + ebih[j]+ebhh[j]
  gemm_bf16_256<<<dim3(256), dim3(512), 0, stream>>>(
      eWih, VV, seq, VV, 1, 1, ebih, ebhh,
      enc_preT, MPRE, FOURH, MPRE, VV, 32, 1);
  // dec_preT[j][t*32+b] = dWih[j,:] . seq[t*32+b,:] + dbih[j]+dbhh[j]
  gemm_bf16_256<<<dim3(256), dim3(512), 0, stream>>>(
      dWih, VV, seq, VV, 0, 1, dbih, dbhh,
      dec_preT, MPRE, FOURH, MPRE, VV, 32, 1);
  // recurrence (encoder then decoder), writes dec_h
  lstm_rec<<<dim3(256), dim3(256), 0, stream>>>(enc_preT, dec_preT, eWhh, dWhh,
                                                hring, dec_h);
  // logits = dec_h @ out_W^T + out_b  (32 mtiles x 19 ntiles = 608 blocks)
  gemm_bf16_256<<<dim3(608), dim3(512), 0, stream>>>(
      dec_h, HH, oW, HH, 0, 0, ob, nullptr,
      logits, VV, MPRE, VV, HH, 19, 0);
  // per-row NLL then deterministic reduce
  loss_rows<<<dim3(8192), dim3(256), 0, stream>>>(seq, logits, nseq, nll);
  final_reduce<<<dim3(1), dim3(256), 0, stream>>>(nll, (float*)d_out);
}